// Round 1
// baseline (403.272 us; speedup 1.0000x reference)
//
#include <hip/hip_runtime.h>

#define DIM 64
#define PRESERVE 0.1f
#define NCOPY 8  // privatized histogram copies (one per XCD, keyed by blockIdx&7)

typedef unsigned short bf16_t;

__device__ __forceinline__ float readlane_f(float v, int l) {
    return __int_as_float(__builtin_amdgcn_readlane(__float_as_int(v), l));
}
__device__ __forceinline__ float bf2f(bf16_t u) {
    return __uint_as_float(((unsigned)u) << 16);
}
__device__ __forceinline__ bf16_t f2bf(float f) {
    unsigned u = __float_as_uint(f);
    unsigned r = (u + 0x7FFFu + ((u >> 16) & 1u)) >> 16;  // RNE
    return (bf16_t)r;
}

// ---------- init ----------
__global__ void k_init(int* cnt8, int n) {
    int i = blockIdx.x * blockDim.x + threadIdx.x;
    if (i < n) cnt8[i] = 0;
}

// ---------- histogram into per-pseudo-XCD privatized counters ----------
// Copy key = blockIdx.x & 7: matches the HW round-robin blockIdx->XCD mapping,
// so each copy's cachelines stay in ONE XCD's L2 (no cross-XCD migration), and
// the key is deterministic so k_fill4 reproduces the exact same mapping.
__global__ void k_hist4(const int4* __restrict__ col4, int* __restrict__ cnt8,
                        int nthreads, int N) {
    int t = blockIdx.x * blockDim.x + threadIdx.x;
    if (t >= nthreads) return;
    int* cur = cnt8 + (size_t)(blockIdx.x & (NCOPY - 1)) * N;
    int4 c = col4[t];
    atomicAdd(&cur[c.x], 1);
    atomicAdd(&cur[c.y], 1);
    atomicAdd(&cur[c.z], 1);
    atomicAdd(&cur[c.w], 1);
}

__global__ void k_hist1(const int* __restrict__ col, int* __restrict__ cnt8,
                        int E, int N) {
    int e = blockIdx.x * blockDim.x + threadIdx.x;
    if (e >= E) return;
    int* cur = cnt8 + (size_t)(blockIdx.x & (NCOPY - 1)) * N;
    atomicAdd(&cur[col[e]], 1);
}

// ---------- 2-level exclusive scan of per-node totals -> offsets ----------
// scan1 sums the 8 copies on the fly; scan3 additionally converts cnt8 into
// per-copy running base positions (so fill's atomic return IS the CSR slot).
__global__ __launch_bounds__(256) void k_scan1(const int* __restrict__ cnt8,
                                               int* __restrict__ offsets,
                                               int* __restrict__ blksum, int n) {
    __shared__ int s[256];
    int t = threadIdx.x;
    int idx = blockIdx.x * 256 + t;
    int v = 0;
    if (idx < n) {
#pragma unroll
        for (int x = 0; x < NCOPY; ++x) v += cnt8[(size_t)x * n + idx];
    }
    s[t] = v;
    __syncthreads();
    for (int off = 1; off < 256; off <<= 1) {
        int x = (t >= off) ? s[t - off] : 0;
        __syncthreads();
        s[t] += x;
        __syncthreads();
    }
    if (idx < n) offsets[idx] = s[t];  // inclusive for now
    if (t == 255) blksum[blockIdx.x] = s[255];
}

__global__ __launch_bounds__(512) void k_scan2(const int* __restrict__ blksum,
                                               int* __restrict__ blkoff, int nblk) {
    __shared__ int s[512];
    int t = threadIdx.x;
    int v = (t < nblk) ? blksum[t] : 0;
    s[t] = v;
    __syncthreads();
    for (int off = 1; off < 512; off <<= 1) {
        int x = (t >= off) ? s[t - off] : 0;
        __syncthreads();
        s[t] += x;
        __syncthreads();
    }
    if (t < nblk) blkoff[t] = s[t] - v;  // exclusive
}

__global__ __launch_bounds__(256) void k_scan3(int* __restrict__ cnt8,
                                               int* __restrict__ offsets,
                                               const int* __restrict__ blkoff,
                                               int n, int E) {
    int idx = blockIdx.x * 256 + threadIdx.x;
    if (idx == 0) offsets[n] = E;
    if (idx >= n) return;
    int c[NCOPY];
    int tot = 0;
#pragma unroll
    for (int x = 0; x < NCOPY; ++x) {
        c[x] = cnt8[(size_t)x * n + idx];
        tot += c[x];
    }
    int off = offsets[idx] - tot + blkoff[blockIdx.x];  // exclusive offset
    offsets[idx] = off;
    // convert counts -> per-copy base cursor (running prefix within bucket)
#pragma unroll
    for (int x = 0; x < NCOPY; ++x) {
        cnt8[(size_t)x * n + idx] = off;
        off += c[x];
    }
}

// ---------- bucket-fill CSR: pos straight from the privatized atomic ----------
__global__ void k_fill4(const int4* __restrict__ row4, const int4* __restrict__ col4,
                        const float4* __restrict__ w4, int* __restrict__ cnt8,
                        int2* __restrict__ sedge, int nthreads, int N) {
    int t = blockIdx.x * blockDim.x + threadIdx.x;
    if (t >= nthreads) return;
    int* cur = cnt8 + (size_t)(blockIdx.x & (NCOPY - 1)) * N;
    int4 r = row4[t];
    int4 c = col4[t];
    float4 w = w4[t];
    int2 p;
    int pos;
    pos = atomicAdd(&cur[c.x], 1); p.x = r.x; p.y = __float_as_int(w.x); sedge[pos] = p;
    pos = atomicAdd(&cur[c.y], 1); p.x = r.y; p.y = __float_as_int(w.y); sedge[pos] = p;
    pos = atomicAdd(&cur[c.z], 1); p.x = r.z; p.y = __float_as_int(w.z); sedge[pos] = p;
    pos = atomicAdd(&cur[c.w], 1); p.x = r.w; p.y = __float_as_int(w.w); sedge[pos] = p;
}

__global__ void k_fill1(const int* __restrict__ row, const int* __restrict__ col,
                        const float* __restrict__ w, int* __restrict__ cnt8,
                        int2* __restrict__ sedge, int E, int N) {
    int e = blockIdx.x * blockDim.x + threadIdx.x;
    if (e >= E) return;
    int* cur = cnt8 + (size_t)(blockIdx.x & (NCOPY - 1)) * N;
    int pos = atomicAdd(&cur[col[e]], 1);
    int2 p;
    p.x = row[e];
    p.y = __float_as_int(w[e]);
    sedge[pos] = p;
}

// ---------- deg -> dinv from CSR (wave per node, no atomics) ----------
__global__ __launch_bounds__(256) void k_deg_seg(const int2* __restrict__ sedge,
                                                 const int* __restrict__ offsets,
                                                 float* __restrict__ dinv, int n) {
    int tid = threadIdx.x;
    int lane = tid & 63;
    int c = blockIdx.x * 4 + (tid >> 6);
    if (c >= n) return;
    int beg = offsets[c];
    int end = offsets[c + 1];
    float s = 0.0f;
    for (int j = beg + lane; j < end; j += 64) s += __int_as_float(sedge[j].y);
    for (int off = 32; off > 0; off >>= 1) s += __shfl_xor(s, off);
    if (lane == 0) {
        float d = 1.0f + s;  // self-loop weight
        dinv[c] = (d > 0.0f) ? rsqrtf(d) : 0.0f;
    }
}

// ---------- xs = bf16( (x @ W) * dinv[row] ) ----------
// Zero-LDS: lane d holds W[:,d] in 64 VGPRs; x broadcast via v_readlane.
__global__ __launch_bounds__(256) void k_mm(
        const float* __restrict__ x, const float* __restrict__ W,
        const float* __restrict__ dinv, bf16_t* __restrict__ xs, int n) {
    int tid = threadIdx.x;
    int lane = tid & 63;
    int waveId = blockIdx.x * 4 + (tid >> 6);
    int nWaves = gridDim.x * 4;

    float Wr[DIM];
#pragma unroll
    for (int k = 0; k < DIM; ++k) Wr[k] = W[k * DIM + lane];

    for (int r0 = waveId * 4; r0 < n; r0 += nWaves * 4) {
        if (r0 + 3 < n) {
            float x0 = x[(size_t)(r0 + 0) * DIM + lane];
            float x1 = x[(size_t)(r0 + 1) * DIM + lane];
            float x2 = x[(size_t)(r0 + 2) * DIM + lane];
            float x3 = x[(size_t)(r0 + 3) * DIM + lane];
            float a0 = 0.f, a1 = 0.f, a2 = 0.f, a3 = 0.f;
#pragma unroll
            for (int k = 0; k < DIM; ++k) {
                float w = Wr[k];
                a0 += readlane_f(x0, k) * w;
                a1 += readlane_f(x1, k) * w;
                a2 += readlane_f(x2, k) * w;
                a3 += readlane_f(x3, k) * w;
            }
            xs[(size_t)(r0 + 0) * DIM + lane] = f2bf(a0 * dinv[r0 + 0]);
            xs[(size_t)(r0 + 1) * DIM + lane] = f2bf(a1 * dinv[r0 + 1]);
            xs[(size_t)(r0 + 2) * DIM + lane] = f2bf(a2 * dinv[r0 + 2]);
            xs[(size_t)(r0 + 3) * DIM + lane] = f2bf(a3 * dinv[r0 + 3]);
        } else {
            for (int r = r0; r < n; ++r) {
                float xv = x[(size_t)r * DIM + lane];
                float a = 0.f;
#pragma unroll
                for (int k = 0; k < DIM; ++k) a += readlane_f(xv, k) * Wr[k];
                xs[(size_t)r * DIM + lane] = f2bf(a * dinv[r]);
            }
        }
    }
}

// ---------- gather (wave per node, lane = dim), bf16 xs rows ----------
// out[c] = 0.9*( dinv[c]*( xs[c] + sum_e w_e*xs[row_e] ) + b ) + 0.1*xprev[c]
__global__ __launch_bounds__(256) void k_gather(
        const bf16_t* __restrict__ xs, const int* __restrict__ offsets,
        const int2* __restrict__ sedge, const float* __restrict__ dinv,
        const float* __restrict__ b, const float* __restrict__ xprev,
        float* __restrict__ out, int n) {
    int tid = threadIdx.x;
    int lane = tid & 63;
    int c = blockIdx.x * 4 + (tid >> 6);
    if (c >= n) return;
    float di = dinv[c];
    float acc = bf2f(xs[(size_t)c * DIM + lane]);
    int beg = offsets[c];
    int end = offsets[c + 1];
    for (int b0 = beg; b0 < end; b0 += 64) {
        int m = end - b0;
        if (m > 64) m = 64;
        int r_l = 0, w_l = 0;
        if (lane < m) {
            int2 p = sedge[b0 + lane];  // coalesced batch load
            r_l = p.x;
            w_l = p.y;
        }
        int j = 0;
        for (; j + 3 < m; j += 4) {
            int r0 = __builtin_amdgcn_readlane(r_l, j);
            int r1 = __builtin_amdgcn_readlane(r_l, j + 1);
            int r2 = __builtin_amdgcn_readlane(r_l, j + 2);
            int r3 = __builtin_amdgcn_readlane(r_l, j + 3);
            float w0 = readlane_f(__int_as_float(w_l), j);
            float w1 = readlane_f(__int_as_float(w_l), j + 1);
            float w2 = readlane_f(__int_as_float(w_l), j + 2);
            float w3 = readlane_f(__int_as_float(w_l), j + 3);
            float a0 = bf2f(xs[(size_t)r0 * DIM + lane]);
            float a1 = bf2f(xs[(size_t)r1 * DIM + lane]);
            float a2 = bf2f(xs[(size_t)r2 * DIM + lane]);
            float a3 = bf2f(xs[(size_t)r3 * DIM + lane]);
            acc += a0 * w0;
            acc += a1 * w1;
            acc += a2 * w2;
            acc += a3 * w3;
        }
        for (; j < m; ++j) {
            int r0 = __builtin_amdgcn_readlane(r_l, j);
            float w0 = readlane_f(__int_as_float(w_l), j);
            acc += bf2f(xs[(size_t)r0 * DIM + lane]) * w0;
        }
    }
    float v = (1.0f - PRESERVE) * (acc * di + b[lane]) + PRESERVE * xprev[(size_t)c * DIM + lane];
    out[(size_t)c * DIM + lane] = v;
}

extern "C" void kernel_launch(void* const* d_in, const int* in_sizes, int n_in,
                              void* d_out, int out_size, void* d_ws, size_t ws_size,
                              hipStream_t stream) {
    const float* x  = (const float*)d_in[0];
    const int*   ei = (const int*)d_in[1];
    const float* ew = (const float*)d_in[2];
    const float* W1 = (const float*)d_in[3];
    const float* b1 = (const float*)d_in[4];
    const float* W2 = (const float*)d_in[5];
    const float* b2 = (const float*)d_in[6];

    const int N = in_sizes[0] / DIM;      // 100000
    const int E = in_sizes[2];            // 1250000
    const int* row = ei;
    const int* col = ei + E;

    // workspace layout (sedge first for 8B alignment)
    int2* sedge   = (int2*)d_ws;                          // E
    float* dinv   = (float*)(sedge + E);                  // N
    float* temp   = dinv + N;                             // N*DIM fp32
    bf16_t* xs    = (bf16_t*)(temp + (size_t)N * DIM);    // N*DIM bf16
    int* cnt8     = (int*)(xs + (size_t)N * DIM);         // NCOPY * N
    int* offsets  = cnt8 + (size_t)NCOPY * N;             // N+1
    int* blksum   = offsets + N + 1;                      // <=640
    int* blkoff   = blksum + 640;                         // <=640

    const int B = 256;
    const int nblkN = (N + B - 1) / B;   // 391 (<=512 for k_scan2)
    const int nblkG = (N + 3) / 4;
    const int nblkMM = 1024;             // grid-stride; 4096 waves

    k_init<<<(NCOPY * N + B - 1) / B, B, 0, stream>>>(cnt8, NCOPY * N);

    // histogram into privatized copies (no rank array needed)
    if ((E & 3) == 0) {
        int nt = E / 4;
        k_hist4<<<(nt + B - 1) / B, B, 0, stream>>>((const int4*)col, cnt8, nt, N);
    } else {
        k_hist1<<<(E + B - 1) / B, B, 0, stream>>>(col, cnt8, E, N);
    }

    // scan totals -> offsets; scan3 also turns cnt8 into per-copy base cursors
    k_scan1<<<nblkN, B, 0, stream>>>(cnt8, offsets, blksum, N);
    k_scan2<<<1, 512, 0, stream>>>(blksum, blkoff, nblkN);
    k_scan3<<<nblkN, B, 0, stream>>>(cnt8, offsets, blkoff, N, E);

    // fill CSR: slot straight from the (L2-local) atomic return.
    // NOTE: grid/block geometry MUST match the hist pass (same edge->copy map).
    if ((E & 3) == 0) {
        int nt = E / 4;
        k_fill4<<<(nt + B - 1) / B, B, 0, stream>>>((const int4*)row, (const int4*)col,
                                                    (const float4*)ew, cnt8, sedge, nt, N);
    } else {
        k_fill1<<<(E + B - 1) / B, B, 0, stream>>>(row, col, ew, cnt8, sedge, E, N);
    }

    // dinv from segmented degree sum
    k_deg_seg<<<nblkG, B, 0, stream>>>(sedge, offsets, dinv, N);

    // layer 1
    k_mm<<<nblkMM, B, 0, stream>>>(x, W1, dinv, xs, N);
    k_gather<<<nblkG, B, 0, stream>>>(xs, offsets, sedge, dinv, b1, x, temp, N);

    // layer 2
    k_mm<<<nblkMM, B, 0, stream>>>(temp, W2, dinv, xs, N);
    k_gather<<<nblkG, B, 0, stream>>>(xs, offsets, sedge, dinv, b2, temp, (float*)d_out, N);
}

// Round 2
// 333.278 us; speedup vs baseline: 1.2100x; 1.2100x over previous
//
#include <hip/hip_runtime.h>

#define DIM 64
#define PRESERVE 0.1f
#define NCOPY 8  // privatized histogram copies, one per physical XCD

typedef unsigned short bf16_t;

__device__ __forceinline__ float readlane_f(float v, int l) {
    return __int_as_float(__builtin_amdgcn_readlane(__float_as_int(v), l));
}
__device__ __forceinline__ float bf2f(bf16_t u) {
    return __uint_as_float(((unsigned)u) << 16);
}
__device__ __forceinline__ bf16_t f2bf(float f) {
    unsigned u = __float_as_uint(f);
    unsigned r = (u + 0x7FFFu + ((u >> 16) & 1u)) >> 16;  // RNE
    return (bf16_t)r;
}
// Physical XCD id (0..7) — wave-uniform scalar read [learn_hip m09].
__device__ __forceinline__ int xcc_id() {
    int x;
    asm volatile("s_getreg_b32 %0, hwreg(HW_REG_XCC_ID)" : "=s"(x));
    return x & (NCOPY - 1);
}

// ---------- init ----------
__global__ void k_init(int* cnt8, int n) {
    int i = blockIdx.x * blockDim.x + threadIdx.x;
    if (i < n) cnt8[i] = 0;
}

// ---------- histogram into per-XCD privatized counters ----------
// Atomics keyed by the REAL XCC_ID: each copy's cachelines are only ever
// touched by one XCD's L2 -> no cross-XCD line migration (the 44MB writeback
// seen in the shared-counter version). The atomic return is the LOCAL rank;
// the copy id is packed into bits [26:24] so the fill pass can reconstruct
// the slot with plain loads (no atomics on its critical path).
__global__ void k_hist4(const int4* __restrict__ col4, int* __restrict__ cnt8,
                        int4* __restrict__ rank4, int nthreads, int N) {
    int t = blockIdx.x * blockDim.x + threadIdx.x;
    if (t >= nthreads) return;
    int x = xcc_id();
    int* cur = cnt8 + (size_t)x * N;
    int tag = x << 24;
    int4 c = col4[t];
    int4 r;
    r.x = atomicAdd(&cur[c.x], 1) | tag;
    r.y = atomicAdd(&cur[c.y], 1) | tag;
    r.z = atomicAdd(&cur[c.z], 1) | tag;
    r.w = atomicAdd(&cur[c.w], 1) | tag;
    rank4[t] = r;
}

__global__ void k_hist1(const int* __restrict__ col, int* __restrict__ cnt8,
                        int* __restrict__ rank, int E, int N) {
    int e = blockIdx.x * blockDim.x + threadIdx.x;
    if (e >= E) return;
    int x = xcc_id();
    int* cur = cnt8 + (size_t)x * N;
    rank[e] = atomicAdd(&cur[col[e]], 1) | (x << 24);
}

// ---------- 2-level exclusive scan of per-node totals -> offsets ----------
// scan1 sums the 8 copies on the fly; scan3 additionally converts cnt8 into
// per-copy base positions (exclusive prefix across copies within each bucket).
__global__ __launch_bounds__(256) void k_scan1(const int* __restrict__ cnt8,
                                               int* __restrict__ offsets,
                                               int* __restrict__ blksum, int n) {
    __shared__ int s[256];
    int t = threadIdx.x;
    int idx = blockIdx.x * 256 + t;
    int v = 0;
    if (idx < n) {
#pragma unroll
        for (int x = 0; x < NCOPY; ++x) v += cnt8[(size_t)x * n + idx];
    }
    s[t] = v;
    __syncthreads();
    for (int off = 1; off < 256; off <<= 1) {
        int x = (t >= off) ? s[t - off] : 0;
        __syncthreads();
        s[t] += x;
        __syncthreads();
    }
    if (idx < n) offsets[idx] = s[t];  // inclusive for now
    if (t == 255) blksum[blockIdx.x] = s[255];
}

__global__ __launch_bounds__(512) void k_scan2(const int* __restrict__ blksum,
                                               int* __restrict__ blkoff, int nblk) {
    __shared__ int s[512];
    int t = threadIdx.x;
    int v = (t < nblk) ? blksum[t] : 0;
    s[t] = v;
    __syncthreads();
    for (int off = 1; off < 512; off <<= 1) {
        int x = (t >= off) ? s[t - off] : 0;
        __syncthreads();
        s[t] += x;
        __syncthreads();
    }
    if (t < nblk) blkoff[t] = s[t] - v;  // exclusive
}

__global__ __launch_bounds__(256) void k_scan3(int* __restrict__ cnt8,
                                               int* __restrict__ offsets,
                                               const int* __restrict__ blkoff,
                                               int n, int E) {
    int idx = blockIdx.x * 256 + threadIdx.x;
    if (idx == 0) offsets[n] = E;
    if (idx >= n) return;
    int c[NCOPY];
    int tot = 0;
#pragma unroll
    for (int x = 0; x < NCOPY; ++x) {
        c[x] = cnt8[(size_t)x * n + idx];
        tot += c[x];
    }
    int off = offsets[idx] - tot + blkoff[blockIdx.x];  // exclusive offset
    offsets[idx] = off;
    // counts -> per-copy base (running prefix within bucket)
#pragma unroll
    for (int x = 0; x < NCOPY; ++x) {
        cnt8[(size_t)x * n + idx] = off;
        off += c[x];
    }
}

// ---------- bucket-fill CSR: atomic-FREE (slot from base + packed rank) ----------
__global__ void k_fill4(const int4* __restrict__ row4, const int4* __restrict__ col4,
                        const float4* __restrict__ w4, const int4* __restrict__ rank4,
                        const int* __restrict__ cnt8, int2* __restrict__ sedge,
                        int nthreads, int N) {
    int t = blockIdx.x * blockDim.x + threadIdx.x;
    if (t >= nthreads) return;
    int4 r = row4[t];
    int4 c = col4[t];
    float4 w = w4[t];
    int4 k = rank4[t];
    int2 p;
    int pos;
    pos = cnt8[(size_t)((k.x >> 24) & 7) * N + c.x] + (k.x & 0xFFFFFF);
    p.x = r.x; p.y = __float_as_int(w.x); sedge[pos] = p;
    pos = cnt8[(size_t)((k.y >> 24) & 7) * N + c.y] + (k.y & 0xFFFFFF);
    p.x = r.y; p.y = __float_as_int(w.y); sedge[pos] = p;
    pos = cnt8[(size_t)((k.z >> 24) & 7) * N + c.z] + (k.z & 0xFFFFFF);
    p.x = r.z; p.y = __float_as_int(w.z); sedge[pos] = p;
    pos = cnt8[(size_t)((k.w >> 24) & 7) * N + c.w] + (k.w & 0xFFFFFF);
    p.x = r.w; p.y = __float_as_int(w.w); sedge[pos] = p;
}

__global__ void k_fill1(const int* __restrict__ row, const int* __restrict__ col,
                        const float* __restrict__ w, const int* __restrict__ rank,
                        const int* __restrict__ cnt8, int2* __restrict__ sedge,
                        int E, int N) {
    int e = blockIdx.x * blockDim.x + threadIdx.x;
    if (e >= E) return;
    int k = rank[e];
    int pos = cnt8[(size_t)((k >> 24) & 7) * N + col[e]] + (k & 0xFFFFFF);
    int2 p;
    p.x = row[e];
    p.y = __float_as_int(w[e]);
    sedge[pos] = p;
}

// ---------- deg -> dinv from CSR (wave per node, no atomics) ----------
__global__ __launch_bounds__(256) void k_deg_seg(const int2* __restrict__ sedge,
                                                 const int* __restrict__ offsets,
                                                 float* __restrict__ dinv, int n) {
    int tid = threadIdx.x;
    int lane = tid & 63;
    int c = blockIdx.x * 4 + (tid >> 6);
    if (c >= n) return;
    int beg = offsets[c];
    int end = offsets[c + 1];
    float s = 0.0f;
    for (int j = beg + lane; j < end; j += 64) s += __int_as_float(sedge[j].y);
    for (int off = 32; off > 0; off >>= 1) s += __shfl_xor(s, off);
    if (lane == 0) {
        float d = 1.0f + s;  // self-loop weight
        dinv[c] = (d > 0.0f) ? rsqrtf(d) : 0.0f;
    }
}

// ---------- xs = bf16( (x @ W) * dinv[row] ) ----------
// Zero-LDS: lane d holds W[:,d] in 64 VGPRs; x broadcast via v_readlane.
__global__ __launch_bounds__(256) void k_mm(
        const float* __restrict__ x, const float* __restrict__ W,
        const float* __restrict__ dinv, bf16_t* __restrict__ xs, int n) {
    int tid = threadIdx.x;
    int lane = tid & 63;
    int waveId = blockIdx.x * 4 + (tid >> 6);
    int nWaves = gridDim.x * 4;

    float Wr[DIM];
#pragma unroll
    for (int k = 0; k < DIM; ++k) Wr[k] = W[k * DIM + lane];

    for (int r0 = waveId * 4; r0 < n; r0 += nWaves * 4) {
        if (r0 + 3 < n) {
            float x0 = x[(size_t)(r0 + 0) * DIM + lane];
            float x1 = x[(size_t)(r0 + 1) * DIM + lane];
            float x2 = x[(size_t)(r0 + 2) * DIM + lane];
            float x3 = x[(size_t)(r0 + 3) * DIM + lane];
            float a0 = 0.f, a1 = 0.f, a2 = 0.f, a3 = 0.f;
#pragma unroll
            for (int k = 0; k < DIM; ++k) {
                float w = Wr[k];
                a0 += readlane_f(x0, k) * w;
                a1 += readlane_f(x1, k) * w;
                a2 += readlane_f(x2, k) * w;
                a3 += readlane_f(x3, k) * w;
            }
            xs[(size_t)(r0 + 0) * DIM + lane] = f2bf(a0 * dinv[r0 + 0]);
            xs[(size_t)(r0 + 1) * DIM + lane] = f2bf(a1 * dinv[r0 + 1]);
            xs[(size_t)(r0 + 2) * DIM + lane] = f2bf(a2 * dinv[r0 + 2]);
            xs[(size_t)(r0 + 3) * DIM + lane] = f2bf(a3 * dinv[r0 + 3]);
        } else {
            for (int r = r0; r < n; ++r) {
                float xv = x[(size_t)r * DIM + lane];
                float a = 0.f;
#pragma unroll
                for (int k = 0; k < DIM; ++k) a += readlane_f(xv, k) * Wr[k];
                xs[(size_t)r * DIM + lane] = f2bf(a * dinv[r]);
            }
        }
    }
}

// ---------- gather (wave per node, lane = dim), bf16 xs rows ----------
// out[c] = 0.9*( dinv[c]*( xs[c] + sum_e w_e*xs[row_e] ) + b ) + 0.1*xprev[c]
__global__ __launch_bounds__(256) void k_gather(
        const bf16_t* __restrict__ xs, const int* __restrict__ offsets,
        const int2* __restrict__ sedge, const float* __restrict__ dinv,
        const float* __restrict__ b, const float* __restrict__ xprev,
        float* __restrict__ out, int n) {
    int tid = threadIdx.x;
    int lane = tid & 63;
    int c = blockIdx.x * 4 + (tid >> 6);
    if (c >= n) return;
    float di = dinv[c];
    float acc = bf2f(xs[(size_t)c * DIM + lane]);
    int beg = offsets[c];
    int end = offsets[c + 1];
    for (int b0 = beg; b0 < end; b0 += 64) {
        int m = end - b0;
        if (m > 64) m = 64;
        int r_l = 0, w_l = 0;
        if (lane < m) {
            int2 p = sedge[b0 + lane];  // coalesced batch load
            r_l = p.x;
            w_l = p.y;
        }
        int j = 0;
        for (; j + 3 < m; j += 4) {
            int r0 = __builtin_amdgcn_readlane(r_l, j);
            int r1 = __builtin_amdgcn_readlane(r_l, j + 1);
            int r2 = __builtin_amdgcn_readlane(r_l, j + 2);
            int r3 = __builtin_amdgcn_readlane(r_l, j + 3);
            float w0 = readlane_f(__int_as_float(w_l), j);
            float w1 = readlane_f(__int_as_float(w_l), j + 1);
            float w2 = readlane_f(__int_as_float(w_l), j + 2);
            float w3 = readlane_f(__int_as_float(w_l), j + 3);
            float a0 = bf2f(xs[(size_t)r0 * DIM + lane]);
            float a1 = bf2f(xs[(size_t)r1 * DIM + lane]);
            float a2 = bf2f(xs[(size_t)r2 * DIM + lane]);
            float a3 = bf2f(xs[(size_t)r3 * DIM + lane]);
            acc += a0 * w0;
            acc += a1 * w1;
            acc += a2 * w2;
            acc += a3 * w3;
        }
        for (; j < m; ++j) {
            int r0 = __builtin_amdgcn_readlane(r_l, j);
            float w0 = readlane_f(__int_as_float(w_l), j);
            acc += bf2f(xs[(size_t)r0 * DIM + lane]) * w0;
        }
    }
    float v = (1.0f - PRESERVE) * (acc * di + b[lane]) + PRESERVE * xprev[(size_t)c * DIM + lane];
    out[(size_t)c * DIM + lane] = v;
}

extern "C" void kernel_launch(void* const* d_in, const int* in_sizes, int n_in,
                              void* d_out, int out_size, void* d_ws, size_t ws_size,
                              hipStream_t stream) {
    const float* x  = (const float*)d_in[0];
    const int*   ei = (const int*)d_in[1];
    const float* ew = (const float*)d_in[2];
    const float* W1 = (const float*)d_in[3];
    const float* b1 = (const float*)d_in[4];
    const float* W2 = (const float*)d_in[5];
    const float* b2 = (const float*)d_in[6];

    const int N = in_sizes[0] / DIM;      // 100000
    const int E = in_sizes[2];            // 1250000
    const int* row = ei;
    const int* col = ei + E;

    // workspace layout (sedge first for 8B alignment)
    int2* sedge   = (int2*)d_ws;                          // E
    float* dinv   = (float*)(sedge + E);                  // N
    float* temp   = dinv + N;                             // N*DIM fp32
    bf16_t* xs    = (bf16_t*)(temp + (size_t)N * DIM);    // N*DIM bf16
    int* rank     = (int*)(xs + (size_t)N * DIM);         // E
    int* cnt8     = rank + E;                             // NCOPY * N
    int* offsets  = cnt8 + (size_t)NCOPY * N;             // N+1
    int* blksum   = offsets + N + 1;                      // <=640
    int* blkoff   = blksum + 640;                         // <=640

    const int B = 256;
    const int nblkN = (N + B - 1) / B;   // 391 (<=512 for k_scan2)
    const int nblkG = (N + 3) / 4;
    const int nblkMM = 1024;             // grid-stride; 4096 waves

    k_init<<<(NCOPY * N + B - 1) / B, B, 0, stream>>>(cnt8, NCOPY * N);

    // histogram into per-XCD copies; rank = local rank | (xcc<<24)
    if ((E & 3) == 0) {
        int nt = E / 4;
        k_hist4<<<(nt + B - 1) / B, B, 0, stream>>>((const int4*)col, cnt8,
                                                    (int4*)rank, nt, N);
    } else {
        k_hist1<<<(E + B - 1) / B, B, 0, stream>>>(col, cnt8, rank, E, N);
    }

    // scan totals -> offsets; scan3 also turns cnt8 into per-copy bases
    k_scan1<<<nblkN, B, 0, stream>>>(cnt8, offsets, blksum, N);
    k_scan2<<<1, 512, 0, stream>>>(blksum, blkoff, nblkN);
    k_scan3<<<nblkN, B, 0, stream>>>(cnt8, offsets, blkoff, N, E);

    // fill CSR: atomic-free (read-only base + rank)
    if ((E & 3) == 0) {
        int nt = E / 4;
        k_fill4<<<(nt + B - 1) / B, B, 0, stream>>>((const int4*)row, (const int4*)col,
                                                    (const float4*)ew, (const int4*)rank,
                                                    cnt8, sedge, nt, N);
    } else {
        k_fill1<<<(E + B - 1) / B, B, 0, stream>>>(row, col, ew, rank, cnt8, sedge, E, N);
    }

    // dinv from segmented degree sum
    k_deg_seg<<<nblkG, B, 0, stream>>>(sedge, offsets, dinv, N);

    // layer 1
    k_mm<<<nblkMM, B, 0, stream>>>(x, W1, dinv, xs, N);
    k_gather<<<nblkG, B, 0, stream>>>(xs, offsets, sedge, dinv, b1, x, temp, N);

    // layer 2
    k_mm<<<nblkMM, B, 0, stream>>>(temp, W2, dinv, xs, N);
    k_gather<<<nblkG, B, 0, stream>>>(xs, offsets, sedge, dinv, b2, temp, (float*)d_out, N);
}

// Round 3
// 297.113 us; speedup vs baseline: 1.3573x; 1.1217x over previous
//
#include <hip/hip_runtime.h>

#define DIM 64
#define PRESERVE 0.1f
#define P_BLK 512     // blocks in count/scatter phases (== threads in k_bscan1)
#define NBMAX 512     // max coarse buckets (N <= 131072)

typedef unsigned short bf16_t;

__device__ __forceinline__ float readlane_f(float v, int l) {
    return __int_as_float(__builtin_amdgcn_readlane(__float_as_int(v), l));
}
__device__ __forceinline__ float bf2f(bf16_t u) {
    return __uint_as_float(((unsigned)u) << 16);
}
__device__ __forceinline__ bf16_t f2bf(float f) {
    unsigned u = __float_as_uint(f);
    unsigned r = (u + 0x7FFFu + ((u >> 16) & 1u)) >> 16;  // RNE
    return (bf16_t)r;
}

// ============ atomic-free CSR build: two-level bucket sort ============
// bucket = col >> 8 (256 nodes per bucket). All counting via LDS atomics;
// every block owns a deterministic exclusive slot range -> zero global atomics.

// ---- phase 1: per-(bucket, block) counts ----
__global__ __launch_bounds__(256) void k_bcount(const int* __restrict__ col,
                                                int* __restrict__ bh,
                                                int E, int nb, int chunk) {
    __shared__ int hist[NBMAX];
    int t = threadIdx.x;
    for (int i = t; i < nb; i += 256) hist[i] = 0;
    __syncthreads();
    int beg = blockIdx.x * chunk;
    int end = beg + chunk;
    if (end > E) end = E;
    for (int i = beg + t; i < end; i += 256) atomicAdd(&hist[col[i] >> 8], 1);
    __syncthreads();
    for (int i = t; i < nb; i += 256) bh[(size_t)i * P_BLK + blockIdx.x] = hist[i];
}

// ---- phase 2a: per-bucket exclusive scan across blocks (grid = nb) ----
__global__ __launch_bounds__(P_BLK) void k_bscan1(int* __restrict__ bh,
                                                  int* __restrict__ btot) {
    __shared__ int s[P_BLK];
    int t = threadIdx.x;
    size_t base = (size_t)blockIdx.x * P_BLK;
    int v = bh[base + t];
    s[t] = v;
    __syncthreads();
    for (int off = 1; off < P_BLK; off <<= 1) {
        int x = (t >= off) ? s[t - off] : 0;
        __syncthreads();
        s[t] += x;
        __syncthreads();
    }
    bh[base + t] = s[t] - v;  // exclusive within bucket
    if (t == P_BLK - 1) btot[blockIdx.x] = s[P_BLK - 1];
}

// ---- phase 2b: exclusive scan of bucket totals -> bucket bases ----
__global__ __launch_bounds__(P_BLK) void k_bscan2(const int* __restrict__ btot,
                                                  int* __restrict__ bbase,
                                                  int nb, int E) {
    __shared__ int s[P_BLK];
    int t = threadIdx.x;
    int v = (t < nb) ? btot[t] : 0;
    s[t] = v;
    __syncthreads();
    for (int off = 1; off < P_BLK; off <<= 1) {
        int x = (t >= off) ? s[t - off] : 0;
        __syncthreads();
        s[t] += x;
        __syncthreads();
    }
    if (t < nb) bbase[t] = s[t] - v;  // exclusive
    if (t == 0) bbase[nb] = E;
}

// ---- phase 3: scatter edges into bucket-grouped arrays ----
__global__ __launch_bounds__(256) void k_bscatter(
        const int* __restrict__ row, const int* __restrict__ col,
        const float* __restrict__ ew, const int* __restrict__ bh,
        const int* __restrict__ bbase, int2* __restrict__ sered,
        int* __restrict__ colb, int E, int nb, int chunk) {
    __shared__ int cur[NBMAX];
    int t = threadIdx.x;
    for (int i = t; i < nb; i += 256)
        cur[i] = bbase[i] + bh[(size_t)i * P_BLK + blockIdx.x];
    __syncthreads();
    int beg = blockIdx.x * chunk;
    int end = beg + chunk;
    if (end > E) end = E;
    for (int i = beg + t; i < end; i += 256) {
        int c = col[i];
        int r = row[i];
        float w = ew[i];
        int slot = atomicAdd(&cur[c >> 8], 1);  // LDS atomic (fast)
        int2 pk;
        pk.x = r;
        pk.y = __float_as_int(w);
        sered[slot] = pk;
        colb[slot] = c;
    }
}

// ---- phase 4: per-bucket local CSR + offsets + dinv (absorbs deg pass) ----
__global__ __launch_bounds__(256) void k_bcsr(
        const int2* __restrict__ sered, const int* __restrict__ colb,
        const int* __restrict__ bbase, int2* __restrict__ sedge,
        int* __restrict__ offsets, float* __restrict__ dinv, int N, int E) {
    __shared__ int cnt[256];
    __shared__ float degw[256];
    __shared__ int sc[256];
    __shared__ int cur[256];
    int t = threadIdx.x;
    int b = blockIdx.x;
    cnt[t] = 0;
    degw[t] = 0.0f;
    __syncthreads();
    int s0 = bbase[b];
    int e0 = bbase[b + 1];
    int nbase = b << 8;
    for (int i = s0 + t; i < e0; i += 256) {
        int loc = colb[i] - nbase;
        atomicAdd(&cnt[loc], 1);
        atomicAdd(&degw[loc], __int_as_float(sered[i].y));
    }
    __syncthreads();
    int v = cnt[t];
    sc[t] = v;
    __syncthreads();
    for (int off = 1; off < 256; off <<= 1) {
        int x = (t >= off) ? sc[t - off] : 0;
        __syncthreads();
        sc[t] += x;
        __syncthreads();
    }
    int excl = sc[t] - v;
    cur[t] = excl;
    int node = nbase + t;
    if (node < N) {
        offsets[node] = s0 + excl;
        dinv[node] = rsqrtf(1.0f + degw[t]);  // self-loop weight 1, deg >= 1
    }
    if (b == 0 && t == 0) offsets[N] = E;
    __syncthreads();
    for (int i = s0 + t; i < e0; i += 256) {
        int loc = colb[i] - nbase;
        int slot = atomicAdd(&cur[loc], 1);  // LDS atomic
        sedge[s0 + slot] = sered[i];
    }
}

// ---------- xs = bf16( (x @ W) * dinv[row] ) ----------
// Zero-LDS: lane d holds W[:,d] in 64 VGPRs; x broadcast via v_readlane.
__global__ __launch_bounds__(256) void k_mm(
        const float* __restrict__ x, const float* __restrict__ W,
        const float* __restrict__ dinv, bf16_t* __restrict__ xs, int n) {
    int tid = threadIdx.x;
    int lane = tid & 63;
    int waveId = blockIdx.x * 4 + (tid >> 6);
    int nWaves = gridDim.x * 4;

    float Wr[DIM];
#pragma unroll
    for (int k = 0; k < DIM; ++k) Wr[k] = W[k * DIM + lane];

    for (int r0 = waveId * 4; r0 < n; r0 += nWaves * 4) {
        if (r0 + 3 < n) {
            float x0 = x[(size_t)(r0 + 0) * DIM + lane];
            float x1 = x[(size_t)(r0 + 1) * DIM + lane];
            float x2 = x[(size_t)(r0 + 2) * DIM + lane];
            float x3 = x[(size_t)(r0 + 3) * DIM + lane];
            float a0 = 0.f, a1 = 0.f, a2 = 0.f, a3 = 0.f;
#pragma unroll
            for (int k = 0; k < DIM; ++k) {
                float w = Wr[k];
                a0 += readlane_f(x0, k) * w;
                a1 += readlane_f(x1, k) * w;
                a2 += readlane_f(x2, k) * w;
                a3 += readlane_f(x3, k) * w;
            }
            xs[(size_t)(r0 + 0) * DIM + lane] = f2bf(a0 * dinv[r0 + 0]);
            xs[(size_t)(r0 + 1) * DIM + lane] = f2bf(a1 * dinv[r0 + 1]);
            xs[(size_t)(r0 + 2) * DIM + lane] = f2bf(a2 * dinv[r0 + 2]);
            xs[(size_t)(r0 + 3) * DIM + lane] = f2bf(a3 * dinv[r0 + 3]);
        } else {
            for (int r = r0; r < n; ++r) {
                float xv = x[(size_t)r * DIM + lane];
                float a = 0.f;
#pragma unroll
                for (int k = 0; k < DIM; ++k) a += readlane_f(xv, k) * Wr[k];
                xs[(size_t)r * DIM + lane] = f2bf(a * dinv[r]);
            }
        }
    }
}

// ---------- gather (wave per node, lane = dim), bf16 xs rows ----------
// out[c] = 0.9*( dinv[c]*( xs[c] + sum_e w_e*xs[row_e] ) + b ) + 0.1*xprev[c]
__global__ __launch_bounds__(256) void k_gather(
        const bf16_t* __restrict__ xs, const int* __restrict__ offsets,
        const int2* __restrict__ sedge, const float* __restrict__ dinv,
        const float* __restrict__ b, const float* __restrict__ xprev,
        float* __restrict__ out, int n) {
    int tid = threadIdx.x;
    int lane = tid & 63;
    int c = blockIdx.x * 4 + (tid >> 6);
    if (c >= n) return;
    float di = dinv[c];
    float acc = bf2f(xs[(size_t)c * DIM + lane]);
    int beg = offsets[c];
    int end = offsets[c + 1];
    for (int b0 = beg; b0 < end; b0 += 64) {
        int m = end - b0;
        if (m > 64) m = 64;
        int r_l = 0, w_l = 0;
        if (lane < m) {
            int2 p = sedge[b0 + lane];  // coalesced batch load
            r_l = p.x;
            w_l = p.y;
        }
        int j = 0;
        for (; j + 3 < m; j += 4) {
            int r0 = __builtin_amdgcn_readlane(r_l, j);
            int r1 = __builtin_amdgcn_readlane(r_l, j + 1);
            int r2 = __builtin_amdgcn_readlane(r_l, j + 2);
            int r3 = __builtin_amdgcn_readlane(r_l, j + 3);
            float w0 = readlane_f(__int_as_float(w_l), j);
            float w1 = readlane_f(__int_as_float(w_l), j + 1);
            float w2 = readlane_f(__int_as_float(w_l), j + 2);
            float w3 = readlane_f(__int_as_float(w_l), j + 3);
            float a0 = bf2f(xs[(size_t)r0 * DIM + lane]);
            float a1 = bf2f(xs[(size_t)r1 * DIM + lane]);
            float a2 = bf2f(xs[(size_t)r2 * DIM + lane]);
            float a3 = bf2f(xs[(size_t)r3 * DIM + lane]);
            acc += a0 * w0;
            acc += a1 * w1;
            acc += a2 * w2;
            acc += a3 * w3;
        }
        for (; j < m; ++j) {
            int r0 = __builtin_amdgcn_readlane(r_l, j);
            float w0 = readlane_f(__int_as_float(w_l), j);
            acc += bf2f(xs[(size_t)r0 * DIM + lane]) * w0;
        }
    }
    float v = (1.0f - PRESERVE) * (acc * di + b[lane]) + PRESERVE * xprev[(size_t)c * DIM + lane];
    out[(size_t)c * DIM + lane] = v;
}

extern "C" void kernel_launch(void* const* d_in, const int* in_sizes, int n_in,
                              void* d_out, int out_size, void* d_ws, size_t ws_size,
                              hipStream_t stream) {
    const float* x  = (const float*)d_in[0];
    const int*   ei = (const int*)d_in[1];
    const float* ew = (const float*)d_in[2];
    const float* W1 = (const float*)d_in[3];
    const float* b1 = (const float*)d_in[4];
    const float* W2 = (const float*)d_in[5];
    const float* b2 = (const float*)d_in[6];

    const int N = in_sizes[0] / DIM;      // 100000
    const int E = in_sizes[2];            // 1250000
    const int* row = ei;
    const int* col = ei + E;

    const int nb = (N + 255) >> 8;        // coarse buckets (391)
    const int chunk = (E + P_BLK - 1) / P_BLK;

    // workspace layout (8B alignment maintained; sered/colb alias temp,
    // which is dead until gather-1 writes it)
    int2* sedge   = (int2*)d_ws;                          // E
    float* dinv   = (float*)(sedge + E);                  // N
    bf16_t* xs    = (bf16_t*)(dinv + N);                  // N*DIM bf16
    float* temp   = (float*)(xs + (size_t)N * DIM);       // N*DIM fp32
    int2* sered   = (int2*)temp;                          //   alias: E int2
    int* colb     = (int*)(sered + E);                    //   alias: E int
    int* offsets  = (int*)(temp + (size_t)N * DIM);       // N+1
    int* bh       = offsets + N + 1;                      // nb * P_BLK
    int* btot     = bh + (size_t)nb * P_BLK;              // nb
    int* bbase    = btot + nb;                            // nb+1

    const int B = 256;
    const int nblkG = (N + 3) / 4;
    const int nblkMM = 1024;             // grid-stride; 4096 waves

    // ---- CSR build (zero global atomics) ----
    k_bcount<<<P_BLK, B, 0, stream>>>(col, bh, E, nb, chunk);
    k_bscan1<<<nb, P_BLK, 0, stream>>>(bh, btot);
    k_bscan2<<<1, P_BLK, 0, stream>>>(btot, bbase, nb, E);
    k_bscatter<<<P_BLK, B, 0, stream>>>(row, col, ew, bh, bbase, sered, colb,
                                        E, nb, chunk);
    k_bcsr<<<nb, B, 0, stream>>>(sered, colb, bbase, sedge, offsets, dinv, N, E);

    // ---- layer 1 ----
    k_mm<<<nblkMM, B, 0, stream>>>(x, W1, dinv, xs, N);
    k_gather<<<nblkG, B, 0, stream>>>(xs, offsets, sedge, dinv, b1, x, temp, N);

    // ---- layer 2 ----
    k_mm<<<nblkMM, B, 0, stream>>>(temp, W2, dinv, xs, N);
    k_gather<<<nblkG, B, 0, stream>>>(xs, offsets, sedge, dinv, b2, temp, (float*)d_out, N);
}